// Round 2
// baseline (1186.342 us; speedup 1.0000x reference)
//
#include <hip/hip_runtime.h>
#include <hip/hip_bf16.h>

typedef __bf16 bf16_t;
typedef __bf16 bf16x8 __attribute__((ext_vector_type(8)));
typedef float  f32x4  __attribute__((ext_vector_type(4)));
typedef unsigned int u32x4 __attribute__((ext_vector_type(4)));

#define NB 2
#define NS 2048
#define ND 1024
#define NH 16
#define NDH 64
#define NP 1024
#define NM (NB*NS)   // 4096 rows total

__device__ __forceinline__ bf16x8 load8(const bf16_t* p) {
  u32x4 u = *(const u32x4*)p;
  return __builtin_bit_cast(bf16x8, u);
}
__device__ __forceinline__ unsigned short bfb(float f) {
  return __builtin_bit_cast(unsigned short, (bf16_t)f);
}

// ---------------------------------------------------------------------------
// Cast x -> bf16 (coalesced float4 -> ushort4)
// ---------------------------------------------------------------------------
__global__ __launch_bounds__(256) void k_cast(
    const float* __restrict__ x, bf16_t* __restrict__ x_bf)
{
  const long NX4 = (long)NM * ND / 4;   // 1M float4 items
  long i0 = (long)blockIdx.x * blockDim.x + threadIdx.x;
  long stride = (long)gridDim.x * blockDim.x;
  for (long i = i0; i < NX4; i += stride) {
    float4 v = ((const float4*)x)[i];
    ushort4 pk;
    pk.x = bfb(v.x); pk.y = bfb(v.y); pk.z = bfb(v.z); pk.w = bfb(v.w);
    ((ushort4*)x_bf)[i] = pk;
  }
}

// ---------------------------------------------------------------------------
// Weight transpose via LDS tile: fp32 [K][N] -> bf16 [N][K], coalesced both ways
// ---------------------------------------------------------------------------
__global__ __launch_bounds__(256) void k_wt(
    const float* __restrict__ Wq, const float* __restrict__ Wk,
    const float* __restrict__ Wv, const float* __restrict__ Wo,
    bf16_t* __restrict__ wtq, bf16_t* __restrict__ wtk,
    bf16_t* __restrict__ wtv, bf16_t* __restrict__ wto)
{
  __shared__ __align__(16) bf16_t tileT[64][72];  // [n][k], stride 144B
  const int w = blockIdx.z;
  const float* src = (w == 0) ? Wq : (w == 1) ? Wk : (w == 2) ? Wv : Wo;
  bf16_t*      dst = (w == 0) ? wtq : (w == 1) ? wtk : (w == 2) ? wtv : wto;
  const int k0 = blockIdx.x * 64, n0 = blockIdx.y * 64;
  const int tid = threadIdx.x;
  const int r = tid >> 4, c4 = (tid & 15) * 4;
#pragma unroll
  for (int rr = 0; rr < 4; ++rr) {
    const int row = rr * 16 + r;                  // k index within tile
    const float4 v = *(const float4*)&src[(long)(k0 + row) * NP + n0 + c4];
    tileT[c4 + 0][row] = (bf16_t)v.x;
    tileT[c4 + 1][row] = (bf16_t)v.y;
    tileT[c4 + 2][row] = (bf16_t)v.z;
    tileT[c4 + 3][row] = (bf16_t)v.w;
  }
  __syncthreads();
  const int nr = tid >> 2, kc = (tid & 3) * 16;
  const bf16x8 p0 = *(const bf16x8*)&tileT[nr][kc];
  const bf16x8 p1 = *(const bf16x8*)&tileT[nr][kc + 8];
  bf16_t* dp = dst + (long)(n0 + nr) * ND + k0 + kc;
  *(bf16x8*)dp = p0;
  *(bf16x8*)(dp + 8) = p1;
}

// ---------------------------------------------------------------------------
// QKV projection. q pre-scaled by 1/8 (exact pow2); k stored [b][h][s][dh];
// v transposed [b][h][dh][s] with pi-PERMUTED s within each 32-block so the
// PV B-fragment k-slots line up with the swapped-QK^T P layout (see k_attn_pv):
//   position p holds actual k = pi(p) = 4*(p>>3) + (p&3) + 16*((p>>2)&1)
//   writer: actual s0 (mult of 4), g=(s0&31)>>2 -> sp=(s0&~31)|((g&3)<<3)|((g>>2)<<2)
// ---------------------------------------------------------------------------
__global__ __launch_bounds__(256) void k_gemm_proj(
    const bf16_t* __restrict__ Abf,
    const bf16_t* __restrict__ wtq, const bf16_t* __restrict__ wtk,
    const bf16_t* __restrict__ wtv,
    bf16_t* __restrict__ q_ws, bf16_t* __restrict__ k_ws, bf16_t* __restrict__ v_ws)
{
  const int z = blockIdx.z;
  const bf16_t* Wt = (z == 0) ? wtq : (z == 1) ? wtk : wtv;
  const int tm = blockIdx.x * 64;
  const int tn = blockIdx.y * 64;
  const int wave = threadIdx.x >> 6;
  const int lane = threadIdx.x & 63;
  const int l16 = lane & 15, quad = lane >> 4;

  const bf16_t* arow = Abf + (long)(tm + wave * 16 + l16) * ND;
  const bf16_t* brow[4];
#pragma unroll
  for (int nt = 0; nt < 4; ++nt)
    brow[nt] = Wt + (long)(tn + nt * 16 + l16) * ND;

  f32x4 acc[4] = {{0,0,0,0},{0,0,0,0},{0,0,0,0},{0,0,0,0}};
  for (int k0 = 0; k0 < ND; k0 += 32) {
    bf16x8 a = load8(arow + k0 + quad * 8);
#pragma unroll
    for (int nt = 0; nt < 4; ++nt) {
      bf16x8 bfrag = load8(brow[nt] + k0 + quad * 8);
      acc[nt] = __builtin_amdgcn_mfma_f32_16x16x32_bf16(a, bfrag, acc[nt], 0, 0, 0);
    }
  }

  const float qscale = (z == 0) ? 0.125f : 1.0f;  // fold 1/sqrt(DH) into Q (exact)
  const int m0 = tm + wave * 16 + quad * 4;
#pragma unroll
  for (int nt = 0; nt < 4; ++nt) {
    const int n = tn + nt * 16 + l16;
    const int h = n >> 6, dh = n & 63;
    if (z == 2) {
      // v transposed + pi-permuted within 32-blocks
      const int b = m0 >> 11, s0 = m0 & 2047;
      const int g = (s0 & 31) >> 2;
      const int sp = (s0 & ~31) | ((g & 3) << 3) | ((g >> 2) << 2);
      ushort4 pk;
      pk.x = bfb(acc[nt][0]); pk.y = bfb(acc[nt][1]);
      pk.z = bfb(acc[nt][2]); pk.w = bfb(acc[nt][3]);
      *(ushort4*)(v_ws + ((long)(b * NH + h) * NDH + dh) * NS + sp) = pk;
    } else {
      bf16_t* dst = (z == 0) ? q_ws : k_ws;
#pragma unroll
      for (int r = 0; r < 4; ++r) {
        const int m = m0 + r;
        const int b = m >> 11, s = m & 2047;
        dst[((long)(b * NH + h) * NS + s) * NDH + dh] = (bf16_t)(acc[nt][r] * qscale);
      }
    }
  }
}

// ---------------------------------------------------------------------------
// Fused attention, SWAPPED QK^T -> zero-shuffle PV:
//   mfma(K_frag, Q_frag) gives D layout col=l16=q, row=quad*4+r=k-index, so
//   each lane holds P[q=l16][k = k0+nt*16+quad*4+r] -- the reduction axis is
//   lane-local. With V's s-index pi-permuted at projection time, af0/af1 for
//   the PV MFMA are直接 pack(p[0],p[1]) / pack(p[2],p[3]): NO LDS transpose,
//   no cross-lane ops in the hot loop. Mask becomes an aligned int4 load.
//   K-split across wave pairs kept for occupancy; attn stores non-temporal
//   (write-once 512 MB stream; keep K/V hot in L2).
// ---------------------------------------------------------------------------
__global__ __launch_bounds__(256) void k_attn_pv(
    const bf16_t* __restrict__ q_ws, const bf16_t* __restrict__ k_ws,
    const bf16_t* __restrict__ v_ws, const int* __restrict__ mask,
    float* __restrict__ attn, bf16_t* __restrict__ o_ws)
{
  __shared__ __align__(16) float red[2][64][16];  // khalf=1 PV partials (8 KB)
  __shared__ float sLDS[2][2][16];                // [khalf][qsub][q16] partial sums
  const int qt = blockIdx.x, h = blockIdx.y, b = blockIdx.z;
  const int wave = threadIdx.x >> 6, lane = threadIdx.x & 63;
  const int l16 = lane & 15, quad = lane >> 4;
  const int qsub = wave & 1, khalf = wave >> 1;
  const int qbase = qt * 32 + qsub * 16;
  const int kbase = khalf * (NS / 2);
  const long headoff = (long)(b * NH + h) * NS;
  const bf16_t* qhead = q_ws + headoff * NDH;
  const bf16_t* khead = k_ws + headoff * NDH;
  const bf16_t* vhead = v_ws + (long)(b * NH + h) * NDH * NS;
  // B-fragment of swapped QK^T: lane l16 = q-row, quad = dh-chunk
  const bf16x8 aq0 = load8(qhead + (long)(qbase + l16) * NDH + quad * 8);
  const bf16x8 aq1 = load8(qhead + (long)(qbase + l16) * NDH + 32 + quad * 8);
  const int* mrow = mask + b * NS;
  float* attn_head = attn + headoff * NS;

  // ---- sweep 1: partial rowsum for q = l16 over this wave's k-half ----
  float srow = 0.f;
  for (int k0 = kbase; k0 < kbase + NS / 2; k0 += 64) {
#pragma unroll
    for (int nt = 0; nt < 4; ++nt) {
      const bf16_t* kr = khead + (long)(k0 + nt * 16 + l16) * NDH;
      f32x4 acc = {0.f, 0.f, 0.f, 0.f};
      __builtin_amdgcn_s_setprio(1);
      acc = __builtin_amdgcn_mfma_f32_16x16x32_bf16(load8(kr + quad * 8), aq0, acc, 0, 0, 0);
      acc = __builtin_amdgcn_mfma_f32_16x16x32_bf16(load8(kr + 32 + quad * 8), aq1, acc, 0, 0, 0);
      __builtin_amdgcn_s_setprio(0);
      const int4 mv = *(const int4*)&mrow[k0 + nt * 16 + quad * 4];
      srow += (mv.x ? __expf(acc[0]) : 0.f) + (mv.y ? __expf(acc[1]) : 0.f)
            + (mv.z ? __expf(acc[2]) : 0.f) + (mv.w ? __expf(acc[3]) : 0.f);
    }
  }
  // reduce across the 4 quads (same q=l16)
  srow += __shfl_xor(srow, 16);
  srow += __shfl_xor(srow, 32);
  if (quad == 0) sLDS[khalf][qsub][l16] = srow;
  __syncthreads();
  const float inv = 1.0f / (sLDS[0][qsub][l16] + sLDS[1][qsub][l16]);

  // ---- sweep 2: recompute, normalize, store attn (nt, vectorized), PV ----
  f32x4 acco[4] = {{0,0,0,0},{0,0,0,0},{0,0,0,0},{0,0,0,0}};
  for (int k0 = kbase; k0 < kbase + NS / 2; k0 += 64) {
    f32x4 e[4];
#pragma unroll
    for (int nt = 0; nt < 4; ++nt) {
      const bf16_t* kr = khead + (long)(k0 + nt * 16 + l16) * NDH;
      f32x4 acc = {0.f, 0.f, 0.f, 0.f};
      __builtin_amdgcn_s_setprio(1);
      acc = __builtin_amdgcn_mfma_f32_16x16x32_bf16(load8(kr + quad * 8), aq0, acc, 0, 0, 0);
      acc = __builtin_amdgcn_mfma_f32_16x16x32_bf16(load8(kr + 32 + quad * 8), aq1, acc, 0, 0, 0);
      __builtin_amdgcn_s_setprio(0);
      const int4 mv = *(const int4*)&mrow[k0 + nt * 16 + quad * 4];
      e[nt][0] = mv.x ? __expf(acc[0]) * inv : 0.f;
      e[nt][1] = mv.y ? __expf(acc[1]) * inv : 0.f;
      e[nt][2] = mv.z ? __expf(acc[2]) * inv : 0.f;
      e[nt][3] = mv.w ? __expf(acc[3]) * inv : 0.f;
      // final attn store: row q=l16, cols k0+nt*16+quad*4.. (16B aligned)
      __builtin_nontemporal_store(
          e[nt], (f32x4*)(attn_head + (long)(qbase + l16) * NS + k0 + nt * 16 + quad * 4));
    }
    // A-fragment for PV comes straight out of registers (V is pi-permuted)
    bf16x8 af0, af1;
#pragma unroll
    for (int i = 0; i < 4; ++i) {
      af0[i] = (bf16_t)e[0][i]; af0[i + 4] = (bf16_t)e[1][i];
      af1[i] = (bf16_t)e[2][i]; af1[i + 4] = (bf16_t)e[3][i];
    }
    __builtin_amdgcn_s_setprio(1);
#pragma unroll
    for (int dt = 0; dt < 4; ++dt) {
      const bf16_t* vr = vhead + (long)(dt * 16 + l16) * NS + k0;
      acco[dt] = __builtin_amdgcn_mfma_f32_16x16x32_bf16(af0, load8(vr + quad * 8), acco[dt], 0, 0, 0);
      acco[dt] = __builtin_amdgcn_mfma_f32_16x16x32_bf16(af1, load8(vr + 32 + quad * 8), acco[dt], 0, 0, 0);
    }
    __builtin_amdgcn_s_setprio(0);
  }

  // ---- cross-wave k-half PV reduce ----
  __syncthreads();
  if (khalf == 1) {
    float* wp = &red[qsub][lane][0];
#pragma unroll
    for (int dt = 0; dt < 4; ++dt) *(f32x4*)(wp + dt * 4) = acco[dt];
  }
  __syncthreads();
  if (khalf == 0) {
    const float* rr = &red[qsub][lane][0];
    const int m0 = qbase + quad * 4;
#pragma unroll
    for (int dt = 0; dt < 4; ++dt) {
      f32x4 o = acco[dt] + *(const f32x4*)(rr + dt * 4);
      const int dh = dt * 16 + l16;
#pragma unroll
      for (int r = 0; r < 4; ++r)
        o_ws[(long)(b * NS + m0 + r) * NP + h * NDH + dh] = (bf16_t)o[r];
    }
  }
}

// ---------------------------------------------------------------------------
// out = O @ Wo  (fp32 store to d_out)
// ---------------------------------------------------------------------------
__global__ __launch_bounds__(256) void k_out(
    const bf16_t* __restrict__ o_ws, const bf16_t* __restrict__ wto,
    float* __restrict__ out)
{
  const int tm = blockIdx.x * 64, tn = blockIdx.y * 64;
  const int wave = threadIdx.x >> 6, lane = threadIdx.x & 63;
  const int l16 = lane & 15, quad = lane >> 4;
  const bf16_t* arow = o_ws + (long)(tm + wave * 16 + l16) * NP;
  const bf16_t* brow[4];
#pragma unroll
  for (int nt = 0; nt < 4; ++nt)
    brow[nt] = wto + (long)(tn + nt * 16 + l16) * NP;

  f32x4 acc[4] = {{0,0,0,0},{0,0,0,0},{0,0,0,0},{0,0,0,0}};
  for (int k0 = 0; k0 < NP; k0 += 32) {
    bf16x8 a = load8(arow + k0 + quad * 8);
#pragma unroll
    for (int nt = 0; nt < 4; ++nt) {
      bf16x8 bfrag = load8(brow[nt] + k0 + quad * 8);
      acc[nt] = __builtin_amdgcn_mfma_f32_16x16x32_bf16(a, bfrag, acc[nt], 0, 0, 0);
    }
  }
  const int m0 = tm + wave * 16 + quad * 4;
#pragma unroll
  for (int nt = 0; nt < 4; ++nt) {
    const int n = tn + nt * 16 + l16;
#pragma unroll
    for (int r = 0; r < 4; ++r)
      out[(long)(m0 + r) * NP + n] = acc[nt][r];
  }
}

// ---------------------------------------------------------------------------
extern "C" void kernel_launch(void* const* d_in, const int* in_sizes, int n_in,
                              void* d_out, int out_size, void* d_ws, size_t ws_size,
                              hipStream_t stream) {
  const float* x    = (const float*)d_in[0];
  const int*   mask = (const int*)d_in[1];
  const float* Wq   = (const float*)d_in[2];
  const float* Wk   = (const float*)d_in[3];
  const float* Wv   = (const float*)d_in[4];
  const float* Wo   = (const float*)d_in[5];

  float* out  = (float*)d_out;                    // [B,S,P] fp32
  float* attn = out + (long)NM * NP;              // [B,H,S,S] fp32

  char* ws = (char*)d_ws;
  const size_t MB = 1024 * 1024;
  bf16_t* x_bf  = (bf16_t*)(ws);                  // 8 MB (aliased as o_ws later)
  bf16_t* wtq   = (bf16_t*)(ws + 8  * MB);        // 2 MB each
  bf16_t* wtk   = (bf16_t*)(ws + 10 * MB);
  bf16_t* wtv   = (bf16_t*)(ws + 12 * MB);
  bf16_t* wto   = (bf16_t*)(ws + 14 * MB);
  bf16_t* q_ws  = (bf16_t*)(ws + 16 * MB);        // 8 MB [b][h][s][dh], pre-scaled 1/8
  bf16_t* k_ws  = (bf16_t*)(ws + 24 * MB);        // 8 MB [b][h][s][dh]
  bf16_t* v_ws  = (bf16_t*)(ws + 32 * MB);        // 8 MB [b][h][dh][s], pi-permuted
  bf16_t* o_ws  = x_bf;  // safe: x_bf consumed by k_gemm_proj before k_attn_pv writes

  k_cast<<<1024, 256, 0, stream>>>(x, x_bf);
  k_wt<<<dim3(ND / 64, NP / 64, 4), 256, 0, stream>>>(
      Wq, Wk, Wv, Wo, wtq, wtk, wtv, wto);
  k_gemm_proj<<<dim3(NM / 64, NP / 64, 3), 256, 0, stream>>>(
      x_bf, wtq, wtk, wtv, q_ws, k_ws, v_ws);
  k_attn_pv<<<dim3(NS / 32, NH, NB), 256, 0, stream>>>(
      q_ws, k_ws, v_ws, mask, attn, o_ws);
  k_out<<<dim3(NM / 64, NP / 64), 256, 0, stream>>>(o_ws, wto, out);
}

// Round 3
// 1179.359 us; speedup vs baseline: 1.0059x; 1.0059x over previous
//
#include <hip/hip_runtime.h>
#include <hip/hip_bf16.h>

typedef __bf16 bf16_t;
typedef __bf16 bf16x8 __attribute__((ext_vector_type(8)));
typedef float  f32x4  __attribute__((ext_vector_type(4)));
typedef unsigned int u32x4 __attribute__((ext_vector_type(4)));

#define NB 2
#define NS 2048
#define ND 1024
#define NH 16
#define NDH 64
#define NP 1024
#define NM (NB*NS)   // 4096 rows total

__device__ __forceinline__ bf16x8 load8(const bf16_t* p) {
  u32x4 u = *(const u32x4*)p;
  return __builtin_bit_cast(bf16x8, u);
}
__device__ __forceinline__ unsigned short bfb(float f) {
  return __builtin_bit_cast(unsigned short, (bf16_t)f);
}

// ---------------------------------------------------------------------------
// Cast x -> bf16 (coalesced float4 -> ushort4)
// ---------------------------------------------------------------------------
__global__ __launch_bounds__(256) void k_cast(
    const float* __restrict__ x, bf16_t* __restrict__ x_bf)
{
  const long NX4 = (long)NM * ND / 4;   // 1M float4 items
  long i0 = (long)blockIdx.x * blockDim.x + threadIdx.x;
  long stride = (long)gridDim.x * blockDim.x;
  for (long i = i0; i < NX4; i += stride) {
    float4 v = ((const float4*)x)[i];
    ushort4 pk;
    pk.x = bfb(v.x); pk.y = bfb(v.y); pk.z = bfb(v.z); pk.w = bfb(v.w);
    ((ushort4*)x_bf)[i] = pk;
  }
}

// ---------------------------------------------------------------------------
// Weight transpose via LDS tile: fp32 [K][N] -> bf16 [N][K], coalesced both ways
// ---------------------------------------------------------------------------
__global__ __launch_bounds__(256) void k_wt(
    const float* __restrict__ Wq, const float* __restrict__ Wk,
    const float* __restrict__ Wv, const float* __restrict__ Wo,
    bf16_t* __restrict__ wtq, bf16_t* __restrict__ wtk,
    bf16_t* __restrict__ wtv, bf16_t* __restrict__ wto)
{
  __shared__ __align__(16) bf16_t tileT[64][72];  // [n][k], stride 144B
  const int w = blockIdx.z;
  const float* src = (w == 0) ? Wq : (w == 1) ? Wk : (w == 2) ? Wv : Wo;
  bf16_t*      dst = (w == 0) ? wtq : (w == 1) ? wtk : (w == 2) ? wtv : wto;
  const int k0 = blockIdx.x * 64, n0 = blockIdx.y * 64;
  const int tid = threadIdx.x;
  const int r = tid >> 4, c4 = (tid & 15) * 4;
#pragma unroll
  for (int rr = 0; rr < 4; ++rr) {
    const int row = rr * 16 + r;                  // k index within tile
    const float4 v = *(const float4*)&src[(long)(k0 + row) * NP + n0 + c4];
    tileT[c4 + 0][row] = (bf16_t)v.x;
    tileT[c4 + 1][row] = (bf16_t)v.y;
    tileT[c4 + 2][row] = (bf16_t)v.z;
    tileT[c4 + 3][row] = (bf16_t)v.w;
  }
  __syncthreads();
  const int nr = tid >> 2, kc = (tid & 3) * 16;
  const bf16x8 p0 = *(const bf16x8*)&tileT[nr][kc];
  const bf16x8 p1 = *(const bf16x8*)&tileT[nr][kc + 8];
  bf16_t* dp = dst + (long)(n0 + nr) * ND + k0 + kc;
  *(bf16x8*)dp = p0;
  *(bf16x8*)(dp + 8) = p1;
}

// ---------------------------------------------------------------------------
// QKV projection. q pre-scaled by 1/8 (exact pow2); k stored [b][h][s][dh];
// v transposed [b][h][dh][s] with pi-PERMUTED s within each 32-block so the
// PV B-fragment k-slots line up with the swapped-QK^T P layout (see k_attn_pv):
//   position p holds actual k = pi(p) = 4*(p>>3) + (p&3) + 16*((p>>2)&1)
//   writer: actual s0 (mult of 4), g=(s0&31)>>2 -> sp=(s0&~31)|((g&3)<<3)|((g>>2)<<2)
// ---------------------------------------------------------------------------
__global__ __launch_bounds__(256) void k_gemm_proj(
    const bf16_t* __restrict__ Abf,
    const bf16_t* __restrict__ wtq, const bf16_t* __restrict__ wtk,
    const bf16_t* __restrict__ wtv,
    bf16_t* __restrict__ q_ws, bf16_t* __restrict__ k_ws, bf16_t* __restrict__ v_ws)
{
  const int z = blockIdx.z;
  const bf16_t* Wt = (z == 0) ? wtq : (z == 1) ? wtk : wtv;
  const int tm = blockIdx.x * 64;
  const int tn = blockIdx.y * 64;
  const int wave = threadIdx.x >> 6;
  const int lane = threadIdx.x & 63;
  const int l16 = lane & 15, quad = lane >> 4;

  const bf16_t* arow = Abf + (long)(tm + wave * 16 + l16) * ND;
  const bf16_t* brow[4];
#pragma unroll
  for (int nt = 0; nt < 4; ++nt)
    brow[nt] = Wt + (long)(tn + nt * 16 + l16) * ND;

  f32x4 acc[4] = {{0,0,0,0},{0,0,0,0},{0,0,0,0},{0,0,0,0}};
  for (int k0 = 0; k0 < ND; k0 += 32) {
    bf16x8 a = load8(arow + k0 + quad * 8);
#pragma unroll
    for (int nt = 0; nt < 4; ++nt) {
      bf16x8 bfrag = load8(brow[nt] + k0 + quad * 8);
      acc[nt] = __builtin_amdgcn_mfma_f32_16x16x32_bf16(a, bfrag, acc[nt], 0, 0, 0);
    }
  }

  const float qscale = (z == 0) ? 0.125f : 1.0f;  // fold 1/sqrt(DH) into Q (exact)
  const int m0 = tm + wave * 16 + quad * 4;
#pragma unroll
  for (int nt = 0; nt < 4; ++nt) {
    const int n = tn + nt * 16 + l16;
    const int h = n >> 6, dh = n & 63;
    if (z == 2) {
      // v transposed + pi-permuted within 32-blocks
      const int b = m0 >> 11, s0 = m0 & 2047;
      const int g = (s0 & 31) >> 2;
      const int sp = (s0 & ~31) | ((g & 3) << 3) | ((g >> 2) << 2);
      ushort4 pk;
      pk.x = bfb(acc[nt][0]); pk.y = bfb(acc[nt][1]);
      pk.z = bfb(acc[nt][2]); pk.w = bfb(acc[nt][3]);
      *(ushort4*)(v_ws + ((long)(b * NH + h) * NDH + dh) * NS + sp) = pk;
    } else {
      bf16_t* dst = (z == 0) ? q_ws : k_ws;
#pragma unroll
      for (int r = 0; r < 4; ++r) {
        const int m = m0 + r;
        const int b = m >> 11, s = m & 2047;
        dst[((long)(b * NH + h) * NS + s) * NDH + dh] = (bf16_t)(acc[nt][r] * qscale);
      }
    }
  }
}

// ---------------------------------------------------------------------------
// Fused attention, SWAPPED QK^T (zero-shuffle PV) + explicit 2-stage pipeline:
//   - mfma(K_frag, Q_frag): lane holds P[q=l16][k lane-local]; V pi-permuted
//     at projection so PV A-frags pack straight from registers. No LDS in loop.
//   - K fragments double-buffered in registers (ka/kb, 2x-unrolled loop, all
//     compile-time indices): tile t+1's loads issue a full iteration early.
//   - V loads issued at TOP of each body, hiding under QK MFMAs + exp/pack.
//   - no setprio, no nontemporal stores (round-2 regressions reverted).
// ---------------------------------------------------------------------------
#define LOADK(kf, kt) do {                                                     \
    _Pragma("unroll")                                                          \
    for (int i_ = 0; i_ < 4; ++i_) {                                           \
      const bf16_t* kr_ = khead + (long)((kt) + i_ * 16 + l16) * NDH;          \
      kf[2*i_]   = load8(kr_ + quad * 8);                                      \
      kf[2*i_+1] = load8(kr_ + 32 + quad * 8);                                 \
    } } while (0)

#define S1BODY(k0c, kf) do {                                                   \
    _Pragma("unroll")                                                          \
    for (int nt = 0; nt < 4; ++nt) {                                           \
      f32x4 acc = {0.f, 0.f, 0.f, 0.f};                                        \
      acc = __builtin_amdgcn_mfma_f32_16x16x32_bf16(kf[2*nt], aq0, acc, 0,0,0);\
      acc = __builtin_amdgcn_mfma_f32_16x16x32_bf16(kf[2*nt+1], aq1, acc, 0,0,0);\
      const int4 mv = *(const int4*)&mrow[(k0c) + nt * 16 + quad * 4];         \
      s0 += mv.x ? __expf(acc[0]) : 0.f;                                       \
      s1 += mv.y ? __expf(acc[1]) : 0.f;                                       \
      s2 += mv.z ? __expf(acc[2]) : 0.f;                                       \
      s3 += mv.w ? __expf(acc[3]) : 0.f;                                       \
    } } while (0)

#define S2BODY(k0c, kf) do {                                                   \
    bf16x8 vf[8];                                                              \
    _Pragma("unroll")                                                          \
    for (int dt = 0; dt < 4; ++dt) {                                           \
      const bf16_t* vr_ = vhead + (long)(dt * 16 + l16) * NS + (k0c);          \
      vf[2*dt]   = load8(vr_ + quad * 8);                                      \
      vf[2*dt+1] = load8(vr_ + 32 + quad * 8);                                 \
    }                                                                          \
    f32x4 e[4];                                                                \
    _Pragma("unroll")                                                          \
    for (int nt = 0; nt < 4; ++nt) {                                           \
      f32x4 acc = {0.f, 0.f, 0.f, 0.f};                                        \
      acc = __builtin_amdgcn_mfma_f32_16x16x32_bf16(kf[2*nt], aq0, acc, 0,0,0);\
      acc = __builtin_amdgcn_mfma_f32_16x16x32_bf16(kf[2*nt+1], aq1, acc, 0,0,0);\
      const int4 mv = *(const int4*)&mrow[(k0c) + nt * 16 + quad * 4];         \
      e[nt][0] = mv.x ? __expf(acc[0]) * inv : 0.f;                            \
      e[nt][1] = mv.y ? __expf(acc[1]) * inv : 0.f;                            \
      e[nt][2] = mv.z ? __expf(acc[2]) * inv : 0.f;                            \
      e[nt][3] = mv.w ? __expf(acc[3]) * inv : 0.f;                            \
      *(f32x4*)(arow_attn + (k0c) + nt * 16 + quad * 4) = e[nt];               \
    }                                                                          \
    bf16x8 af0, af1;                                                           \
    _Pragma("unroll")                                                          \
    for (int i_ = 0; i_ < 4; ++i_) {                                           \
      af0[i_] = (bf16_t)e[0][i_]; af0[i_+4] = (bf16_t)e[1][i_];                \
      af1[i_] = (bf16_t)e[2][i_]; af1[i_+4] = (bf16_t)e[3][i_];                \
    }                                                                          \
    _Pragma("unroll")                                                          \
    for (int dt = 0; dt < 4; ++dt) {                                           \
      acco[dt] = __builtin_amdgcn_mfma_f32_16x16x32_bf16(af0, vf[2*dt], acco[dt], 0,0,0);   \
      acco[dt] = __builtin_amdgcn_mfma_f32_16x16x32_bf16(af1, vf[2*dt+1], acco[dt], 0,0,0); \
    } } while (0)

__global__ __launch_bounds__(256) void k_attn_pv(
    const bf16_t* __restrict__ q_ws, const bf16_t* __restrict__ k_ws,
    const bf16_t* __restrict__ v_ws, const int* __restrict__ mask,
    float* __restrict__ attn, bf16_t* __restrict__ o_ws)
{
  __shared__ __align__(16) float red[2][64][16];  // khalf=1 PV partials (8 KB)
  __shared__ float sLDS[2][2][16];                // [khalf][qsub][q16] partial sums
  const int qt = blockIdx.x, h = blockIdx.y, b = blockIdx.z;
  const int wave = threadIdx.x >> 6, lane = threadIdx.x & 63;
  const int l16 = lane & 15, quad = lane >> 4;
  const int qsub = wave & 1, khalf = wave >> 1;
  const int qbase = qt * 32 + qsub * 16;
  const int kbase = khalf * (NS / 2);
  const int kend  = kbase + NS / 2;
  const long headoff = (long)(b * NH + h) * NS;
  const bf16_t* qhead = q_ws + headoff * NDH;
  const bf16_t* khead = k_ws + headoff * NDH;
  const bf16_t* vhead = v_ws + (long)(b * NH + h) * NDH * NS;
  // B-fragment of swapped QK^T: lane l16 = q-row, quad = dh-chunk
  const bf16x8 aq0 = load8(qhead + (long)(qbase + l16) * NDH + quad * 8);
  const bf16x8 aq1 = load8(qhead + (long)(qbase + l16) * NDH + 32 + quad * 8);
  const int* mrow = mask + b * NS;
  float* arow_attn = attn + (headoff + qbase + l16) * NS;

  bf16x8 ka[8], kb[8];

  // ---- sweep 1: partial rowsum for q = l16 over this wave's k-half ----
  float s0 = 0.f, s1 = 0.f, s2 = 0.f, s3 = 0.f;
  LOADK(ka, kbase);
  for (int k0 = kbase; k0 < kend; k0 += 128) {
    LOADK(kb, k0 + 64);            // prefetch tile t+1 while computing tile t
    S1BODY(k0, ka);
    const int kn = (k0 + 128 < kend) ? k0 + 128 : kbase;  // clamped (dead on last)
    LOADK(ka, kn);
    S1BODY(k0 + 64, kb);
  }
  float srow = (s0 + s1) + (s2 + s3);
  srow += __shfl_xor(srow, 16);
  srow += __shfl_xor(srow, 32);
  if (quad == 0) sLDS[khalf][qsub][l16] = srow;
  __syncthreads();
  const float inv = 1.0f / (sLDS[0][qsub][l16] + sLDS[1][qsub][l16]);

  // ---- sweep 2: recompute, normalize, store attn, PV (pipelined) ----
  f32x4 acco[4] = {{0,0,0,0},{0,0,0,0},{0,0,0,0},{0,0,0,0}};
  LOADK(ka, kbase);
  for (int k0 = kbase; k0 < kend; k0 += 128) {
    LOADK(kb, k0 + 64);
    S2BODY(k0, ka);
    const int kn = (k0 + 128 < kend) ? k0 + 128 : kbase;
    LOADK(ka, kn);
    S2BODY(k0 + 64, kb);
  }

  // ---- cross-wave k-half PV reduce ----
  __syncthreads();
  if (khalf == 1) {
    float* wp = &red[qsub][lane][0];
#pragma unroll
    for (int dt = 0; dt < 4; ++dt) *(f32x4*)(wp + dt * 4) = acco[dt];
  }
  __syncthreads();
  if (khalf == 0) {
    const float* rr = &red[qsub][lane][0];
    const int m0 = qbase + quad * 4;
#pragma unroll
    for (int dt = 0; dt < 4; ++dt) {
      f32x4 o = acco[dt] + *(const f32x4*)(rr + dt * 4);
      const int dh = dt * 16 + l16;
#pragma unroll
      for (int r = 0; r < 4; ++r)
        o_ws[(long)(b * NS + m0 + r) * NP + h * NDH + dh] = (bf16_t)o[r];
    }
  }
}

// ---------------------------------------------------------------------------
// out = O @ Wo  (fp32 store to d_out)
// ---------------------------------------------------------------------------
__global__ __launch_bounds__(256) void k_out(
    const bf16_t* __restrict__ o_ws, const bf16_t* __restrict__ wto,
    float* __restrict__ out)
{
  const int tm = blockIdx.x * 64, tn = blockIdx.y * 64;
  const int wave = threadIdx.x >> 6, lane = threadIdx.x & 63;
  const int l16 = lane & 15, quad = lane >> 4;
  const bf16_t* arow = o_ws + (long)(tm + wave * 16 + l16) * NP;
  const bf16_t* brow[4];
#pragma unroll
  for (int nt = 0; nt < 4; ++nt)
    brow[nt] = wto + (long)(tn + nt * 16 + l16) * NP;

  f32x4 acc[4] = {{0,0,0,0},{0,0,0,0},{0,0,0,0},{0,0,0,0}};
  for (int k0 = 0; k0 < NP; k0 += 32) {
    bf16x8 a = load8(arow + k0 + quad * 8);
#pragma unroll
    for (int nt = 0; nt < 4; ++nt) {
      bf16x8 bfrag = load8(brow[nt] + k0 + quad * 8);
      acc[nt] = __builtin_amdgcn_mfma_f32_16x16x32_bf16(a, bfrag, acc[nt], 0, 0, 0);
    }
  }
  const int m0 = tm + wave * 16 + quad * 4;
#pragma unroll
  for (int nt = 0; nt < 4; ++nt) {
    const int n = tn + nt * 16 + l16;
#pragma unroll
    for (int r = 0; r < 4; ++r)
      out[(long)(m0 + r) * NP + n] = acc[nt][r];
  }
}

// ---------------------------------------------------------------------------
extern "C" void kernel_launch(void* const* d_in, const int* in_sizes, int n_in,
                              void* d_out, int out_size, void* d_ws, size_t ws_size,
                              hipStream_t stream) {
  const float* x    = (const float*)d_in[0];
  const int*   mask = (const int*)d_in[1];
  const float* Wq   = (const float*)d_in[2];
  const float* Wk   = (const float*)d_in[3];
  const float* Wv   = (const float*)d_in[4];
  const float* Wo   = (const float*)d_in[5];

  float* out  = (float*)d_out;                    // [B,S,P] fp32
  float* attn = out + (long)NM * NP;              // [B,H,S,S] fp32

  char* ws = (char*)d_ws;
  const size_t MB = 1024 * 1024;
  bf16_t* x_bf  = (bf16_t*)(ws);                  // 8 MB (aliased as o_ws later)
  bf16_t* wtq   = (bf16_t*)(ws + 8  * MB);        // 2 MB each
  bf16_t* wtk   = (bf16_t*)(ws + 10 * MB);
  bf16_t* wtv   = (bf16_t*)(ws + 12 * MB);
  bf16_t* wto   = (bf16_t*)(ws + 14 * MB);
  bf16_t* q_ws  = (bf16_t*)(ws + 16 * MB);        // 8 MB [b][h][s][dh], pre-scaled 1/8
  bf16_t* k_ws  = (bf16_t*)(ws + 24 * MB);        // 8 MB [b][h][s][dh]
  bf16_t* v_ws  = (bf16_t*)(ws + 32 * MB);        // 8 MB [b][h][dh][s], pi-permuted
  bf16_t* o_ws  = x_bf;  // safe: x_bf consumed by k_gemm_proj before k_attn_pv writes

  k_cast<<<1024, 256, 0, stream>>>(x, x_bf);
  k_wt<<<dim3(ND / 64, NP / 64, 4), 256, 0, stream>>>(
      Wq, Wk, Wv, Wo, wtq, wtk, wtv, wto);
  k_gemm_proj<<<dim3(NM / 64, NP / 64, 3), 256, 0, stream>>>(
      x_bf, wtq, wtk, wtv, q_ws, k_ws, v_ws);
  k_attn_pv<<<dim3(NS / 32, NH, NB), 256, 0, stream>>>(
      q_ws, k_ws, v_ws, mask, attn, o_ws);
  k_out<<<dim3(NM / 64, NP / 64), 256, 0, stream>>>(o_ws, wto, out);
}

// Round 4
// 934.702 us; speedup vs baseline: 1.2692x; 1.2617x over previous
//
#include <hip/hip_runtime.h>
#include <hip/hip_bf16.h>

typedef __bf16 bf16_t;
typedef __bf16 bf16x8 __attribute__((ext_vector_type(8)));
typedef float  f32x4  __attribute__((ext_vector_type(4)));
typedef unsigned int u32x4 __attribute__((ext_vector_type(4)));

#define NB 2
#define NS 2048
#define ND 1024
#define NH 16
#define NDH 64
#define NP 1024
#define NM (NB*NS)   // 4096 rows total

#define MFMA16 __builtin_amdgcn_mfma_f32_16x16x32_bf16

__device__ __forceinline__ bf16x8 load8(const bf16_t* p) {
  u32x4 u = *(const u32x4*)p;
  return __builtin_bit_cast(bf16x8, u);
}
__device__ __forceinline__ unsigned short bfb(float f) {
  return __builtin_bit_cast(unsigned short, (bf16_t)f);
}
// async global->LDS, 16B per lane; LDS dest must be wave-uniform base
__device__ __forceinline__ void gld16(const bf16_t* g, bf16_t* l) {
  __builtin_amdgcn_global_load_lds(
      (const __attribute__((address_space(1))) void*)g,
      (__attribute__((address_space(3))) void*)l, 16, 0, 0);
}

// ---------------------------------------------------------------------------
// Cast x -> bf16 (coalesced float4 -> ushort4)
// ---------------------------------------------------------------------------
__global__ __launch_bounds__(256) void k_cast(
    const float* __restrict__ x, bf16_t* __restrict__ x_bf)
{
  const long NX4 = (long)NM * ND / 4;   // 1M float4 items
  long i0 = (long)blockIdx.x * blockDim.x + threadIdx.x;
  long stride = (long)gridDim.x * blockDim.x;
  for (long i = i0; i < NX4; i += stride) {
    float4 v = ((const float4*)x)[i];
    ushort4 pk;
    pk.x = bfb(v.x); pk.y = bfb(v.y); pk.z = bfb(v.z); pk.w = bfb(v.w);
    ((ushort4*)x_bf)[i] = pk;
  }
}

// ---------------------------------------------------------------------------
// Weight transpose via LDS tile: fp32 [K][N] -> bf16 [N][K], coalesced both ways
// ---------------------------------------------------------------------------
__global__ __launch_bounds__(256) void k_wt(
    const float* __restrict__ Wq, const float* __restrict__ Wk,
    const float* __restrict__ Wv, const float* __restrict__ Wo,
    bf16_t* __restrict__ wtq, bf16_t* __restrict__ wtk,
    bf16_t* __restrict__ wtv, bf16_t* __restrict__ wto)
{
  __shared__ __align__(16) bf16_t tileT[64][72];  // [n][k], stride 144B
  const int w = blockIdx.z;
  const float* src = (w == 0) ? Wq : (w == 1) ? Wk : (w == 2) ? Wv : Wo;
  bf16_t*      dst = (w == 0) ? wtq : (w == 1) ? wtk : (w == 2) ? wtv : wto;
  const int k0 = blockIdx.x * 64, n0 = blockIdx.y * 64;
  const int tid = threadIdx.x;
  const int r = tid >> 4, c4 = (tid & 15) * 4;
#pragma unroll
  for (int rr = 0; rr < 4; ++rr) {
    const int row = rr * 16 + r;                  // k index within tile
    const float4 v = *(const float4*)&src[(long)(k0 + row) * NP + n0 + c4];
    tileT[c4 + 0][row] = (bf16_t)v.x;
    tileT[c4 + 1][row] = (bf16_t)v.y;
    tileT[c4 + 2][row] = (bf16_t)v.z;
    tileT[c4 + 3][row] = (bf16_t)v.w;
  }
  __syncthreads();
  const int nr = tid >> 2, kc = (tid & 3) * 16;
  const bf16x8 p0 = *(const bf16x8*)&tileT[nr][kc];
  const bf16x8 p1 = *(const bf16x8*)&tileT[nr][kc + 8];
  bf16_t* dp = dst + (long)(n0 + nr) * ND + k0 + kc;
  *(bf16x8*)dp = p0;
  *(bf16x8*)(dp + 8) = p1;
}

// ---------------------------------------------------------------------------
// m97-style 128x128 GEMM core: C = A[M x K] * Bt[N x K]^T, bf16 in, f32 acc.
// 4 waves (2x2), BK=64, 32 KB linear LDS, global_load_lds width-16 staging,
// 2-barrier K-loop (compiler emits vmcnt(0)+lgkmcnt(0) before s_barrier).
// Staging chunk cc (0..15) = LDS rows cc*8..cc*8+7; lane writes 16B at
// base+lane*16 -> row cc*8+lane/8, col (lane&7)*8 -> global src matches.
// ---------------------------------------------------------------------------
template <int KDIM>
__device__ __forceinline__ void gemm_128x128(
    const bf16_t* __restrict__ A, const bf16_t* __restrict__ B,
    int tm, int tn, bf16_t (&As)[128][64], bf16_t (&Bs)[128][64],
    f32x4 (&acc)[4][4])
{
  const int wave = threadIdx.x >> 6, lane = threadIdx.x & 63;
  const int l16 = lane & 15, quad = lane >> 4;
  const int wr = wave >> 1, wc = wave & 1;
  const int srcrow = lane >> 3, srccol = (lane & 7) * 8;

  for (int ks = 0; ks < KDIM; ks += 64) {
#pragma unroll
    for (int i = 0; i < 4; ++i) {
      const int cc = i * 4 + wave;   // wave-uniform LDS dest ✓
      gld16(A + (long)(tm + cc * 8 + srcrow) * KDIM + ks + srccol, &As[cc * 8][0]);
      gld16(B + (long)(tn + cc * 8 + srcrow) * KDIM + ks + srccol, &Bs[cc * 8][0]);
    }
    __syncthreads();   // drains vmcnt -> LDS tiles ready
#pragma unroll
    for (int s = 0; s < 2; ++s) {
      bf16x8 aF[4], bF[4];
#pragma unroll
      for (int t = 0; t < 4; ++t)
        aF[t] = load8(&As[wr * 64 + t * 16 + l16][s * 32 + quad * 8]);
#pragma unroll
      for (int t = 0; t < 4; ++t)
        bF[t] = load8(&Bs[wc * 64 + t * 16 + l16][s * 32 + quad * 8]);
#pragma unroll
      for (int mi = 0; mi < 4; ++mi)
#pragma unroll
        for (int ni = 0; ni < 4; ++ni)
          acc[mi][ni] = MFMA16(aF[mi], bF[ni], acc[mi][ni], 0, 0, 0);
    }
    __syncthreads();   // before next stage overwrites LDS
  }
}

// ---------------------------------------------------------------------------
// QKV projection: 128x128 LDS-staged GEMM. q pre-scaled 1/8 (exact pow2);
// q,k stored [b][h][s][dh]; v transposed [b][h][dh][s] (plain, no permute).
// ---------------------------------------------------------------------------
__global__ __launch_bounds__(256) void k_gemm_proj(
    const bf16_t* __restrict__ Abf,
    const bf16_t* __restrict__ wtq, const bf16_t* __restrict__ wtk,
    const bf16_t* __restrict__ wtv,
    bf16_t* __restrict__ q_ws, bf16_t* __restrict__ k_ws, bf16_t* __restrict__ v_ws)
{
  __shared__ __align__(16) bf16_t As[128][64];
  __shared__ __align__(16) bf16_t Bs[128][64];
  const int z = blockIdx.z;
  const bf16_t* Wt = (z == 0) ? wtq : (z == 1) ? wtk : wtv;
  const int tm = blockIdx.x * 128, tn = blockIdx.y * 128;

  f32x4 acc[4][4];
#pragma unroll
  for (int i = 0; i < 4; ++i)
#pragma unroll
    for (int j = 0; j < 4; ++j) acc[i][j] = (f32x4){0.f, 0.f, 0.f, 0.f};

  gemm_128x128<ND>(Abf, Wt, tm, tn, As, Bs, acc);

  const int wave = threadIdx.x >> 6, lane = threadIdx.x & 63;
  const int l16 = lane & 15, quad = lane >> 4;
  const int wr = wave >> 1, wc = wave & 1;
  const float qscale = (z == 0) ? 0.125f : 1.0f;
#pragma unroll
  for (int mi = 0; mi < 4; ++mi) {
    const int m0 = tm + wr * 64 + mi * 16 + quad * 4;
#pragma unroll
    for (int ni = 0; ni < 4; ++ni) {
      const int n = tn + wc * 64 + ni * 16 + l16;
      const int h = n >> 6, dh = n & 63;
      if (z == 2) {
        // v transposed: rows m0..m0+3 are consecutive s
        const int b = m0 >> 11, s0 = m0 & 2047;
        ushort4 pk;
        pk.x = bfb(acc[mi][ni][0]); pk.y = bfb(acc[mi][ni][1]);
        pk.z = bfb(acc[mi][ni][2]); pk.w = bfb(acc[mi][ni][3]);
        *(ushort4*)(v_ws + ((long)(b * NH + h) * NDH + dh) * NS + s0) = pk;
      } else {
        bf16_t* dst = (z == 0) ? q_ws : k_ws;
#pragma unroll
        for (int r = 0; r < 4; ++r) {
          const int m = m0 + r;
          const int b = m >> 11, s = m & 2047;
          dst[((long)(b * NH + h) * NS + s) * NDH + dh] = (bf16_t)(acc[mi][ni][r] * qscale);
        }
      }
    }
  }
}

// ---------------------------------------------------------------------------
// Fused attention (round-1 variant, best measured: 401 us).
// K-split across wave pairs; sweep 1 exact rowsums; sweep 2 recompute,
// normalize, vectorized f32x4 attn stores, per-wave LDS transpose, PV MFMA;
// cross-wave k-half PV reduce via LDS.
// ---------------------------------------------------------------------------
__global__ __launch_bounds__(256) void k_attn_pv(
    const bf16_t* __restrict__ q_ws, const bf16_t* __restrict__ k_ws,
    const bf16_t* __restrict__ v_ws, const int* __restrict__ mask,
    float* __restrict__ attn, bf16_t* __restrict__ o_ws)
{
  __shared__ __align__(16) float eLDS[4][16][68];  // per-wave 16x64 tile, +4 pad
  __shared__ float sLDS[2][2][16];                 // [khalf][qsub][row16] partial sums
  const int qt = blockIdx.x, h = blockIdx.y, b = blockIdx.z;
  const int wave = threadIdx.x >> 6, lane = threadIdx.x & 63;
  const int l16 = lane & 15, quad = lane >> 4;
  const int qsub = wave & 1, khalf = wave >> 1;
  const int qbase = qt * 32 + qsub * 16;
  const int kbase = khalf * (NS / 2);
  const long headoff = (long)(b * NH + h) * NS;
  const bf16_t* qhead = q_ws + headoff * NDH;
  const bf16_t* khead = k_ws + headoff * NDH;
  const bf16_t* vhead = v_ws + (long)(b * NH + h) * NDH * NS;
  const bf16x8 aq0 = load8(qhead + (long)(qbase + l16) * NDH + quad * 8);
  const bf16x8 aq1 = load8(qhead + (long)(qbase + l16) * NDH + 32 + quad * 8);
  const int* mrow = mask + b * NS;
  const int m0 = qbase + quad * 4;
  float* attn_head = attn + headoff * NS;

  // ---- sweep 1: partial rowsums over this wave's k-half ----
  float srow[4] = {0.f, 0.f, 0.f, 0.f};
  for (int k0 = kbase; k0 < kbase + NS / 2; k0 += 64) {
#pragma unroll
    for (int nt = 0; nt < 4; ++nt) {
      const bf16_t* kr = khead + (long)(k0 + nt * 16 + l16) * NDH;
      f32x4 acc = {0.f, 0.f, 0.f, 0.f};
      acc = __builtin_amdgcn_mfma_f32_16x16x32_bf16(aq0, load8(kr + quad * 8), acc, 0, 0, 0);
      acc = __builtin_amdgcn_mfma_f32_16x16x32_bf16(aq1, load8(kr + 32 + quad * 8), acc, 0, 0, 0);
      if (mrow[k0 + nt * 16 + l16]) {
#pragma unroll
        for (int r = 0; r < 4; ++r) srow[r] += __expf(acc[r]);
      }
    }
  }
#pragma unroll
  for (int r = 0; r < 4; ++r) {
    float v = srow[r];
    v += __shfl_xor(v, 1); v += __shfl_xor(v, 2);
    v += __shfl_xor(v, 4); v += __shfl_xor(v, 8);
    srow[r] = v;   // partial rowsum for row m0+r over this k-half
  }
  if (l16 == 0) {
#pragma unroll
    for (int r = 0; r < 4; ++r) sLDS[khalf][qsub][quad * 4 + r] = srow[r];
  }
  __syncthreads();
  float inv[4];
#pragma unroll
  for (int r = 0; r < 4; ++r)
    inv[r] = 1.0f / (sLDS[0][qsub][quad * 4 + r] + sLDS[1][qsub][quad * 4 + r]);

  // ---- sweep 2: recompute, normalize, store attn (vectorized), PV ----
  f32x4 acco[4] = {{0,0,0,0},{0,0,0,0},{0,0,0,0},{0,0,0,0}};
  for (int k0 = kbase; k0 < kbase + NS / 2; k0 += 64) {
#pragma unroll
    for (int nt = 0; nt < 4; ++nt) {
      const bf16_t* kr = khead + (long)(k0 + nt * 16 + l16) * NDH;
      f32x4 acc = {0.f, 0.f, 0.f, 0.f};
      acc = __builtin_amdgcn_mfma_f32_16x16x32_bf16(aq0, load8(kr + quad * 8), acc, 0, 0, 0);
      acc = __builtin_amdgcn_mfma_f32_16x16x32_bf16(aq1, load8(kr + 32 + quad * 8), acc, 0, 0, 0);
      const int mv = mrow[k0 + nt * 16 + l16];
#pragma unroll
      for (int r = 0; r < 4; ++r) {
        float e = mv ? __expf(acc[r]) * inv[r] : 0.0f;
        eLDS[wave][quad * 4 + r][nt * 16 + l16] = e;
      }
    }
    // per-wave LDS round-trip: this wave reads only rows it just wrote
    const float* rp = &eLDS[wave][l16][0];
    f32x4 e0 = *(const f32x4*)(rp + quad * 8);
    f32x4 e1 = *(const f32x4*)(rp + quad * 8 + 4);
    f32x4 e2 = *(const f32x4*)(rp + 32 + quad * 8);
    f32x4 e3 = *(const f32x4*)(rp + 32 + quad * 8 + 4);
    // vectorized final attn store from A-layout registers (4x dwordx4 / lane)
    float* ap = attn_head + (long)(qbase + l16) * NS + k0;
    *(f32x4*)(ap + quad * 8) = e0;
    *(f32x4*)(ap + quad * 8 + 4) = e1;
    *(f32x4*)(ap + 32 + quad * 8) = e2;
    *(f32x4*)(ap + 32 + quad * 8 + 4) = e3;
    bf16x8 af0, af1;
#pragma unroll
    for (int i = 0; i < 4; ++i) {
      af0[i] = (bf16_t)e0[i]; af0[i + 4] = (bf16_t)e1[i];
      af1[i] = (bf16_t)e2[i]; af1[i + 4] = (bf16_t)e3[i];
    }
#pragma unroll
    for (int nt = 0; nt < 4; ++nt) {
      const bf16_t* vr = vhead + (long)(nt * 16 + l16) * NS + k0;
      acco[nt] = __builtin_amdgcn_mfma_f32_16x16x32_bf16(af0, load8(vr + quad * 8), acco[nt], 0, 0, 0);
      acco[nt] = __builtin_amdgcn_mfma_f32_16x16x32_bf16(af1, load8(vr + 32 + quad * 8), acco[nt], 0, 0, 0);
    }
  }

  // ---- cross-wave k-half PV reduce (reuse eLDS as scratch) ----
  __syncthreads();
  float* red = &eLDS[0][0][0];
  if (khalf == 1) {
    float* wp = red + ((qsub * 64 + lane) * 16);
#pragma unroll
    for (int nt = 0; nt < 4; ++nt) *(f32x4*)(wp + nt * 4) = acco[nt];
  }
  __syncthreads();
  if (khalf == 0) {
    const float* rr = red + ((qsub * 64 + lane) * 16);
#pragma unroll
    for (int nt = 0; nt < 4; ++nt) {
      f32x4 o = acco[nt] + *(const f32x4*)(rr + nt * 4);
      const int dh = nt * 16 + l16;
#pragma unroll
      for (int r = 0; r < 4; ++r)
        o_ws[(long)(b * NS + m0 + r) * NP + h * NDH + dh] = (bf16_t)o[r];
    }
  }
}

// ---------------------------------------------------------------------------
// out = O @ Wo  (128x128 LDS-staged GEMM, fp32 store to d_out)
// ---------------------------------------------------------------------------
__global__ __launch_bounds__(256) void k_out(
    const bf16_t* __restrict__ o_ws, const bf16_t* __restrict__ wto,
    float* __restrict__ out)
{
  __shared__ __align__(16) bf16_t As[128][64];
  __shared__ __align__(16) bf16_t Bs[128][64];
  const int tm = blockIdx.x * 128, tn = blockIdx.y * 128;

  f32x4 acc[4][4];
#pragma unroll
  for (int i = 0; i < 4; ++i)
#pragma unroll
    for (int j = 0; j < 4; ++j) acc[i][j] = (f32x4){0.f, 0.f, 0.f, 0.f};

  gemm_128x128<NP>(o_ws, wto, tm, tn, As, Bs, acc);

  const int wave = threadIdx.x >> 6, lane = threadIdx.x & 63;
  const int l16 = lane & 15, quad = lane >> 4;
  const int wr = wave >> 1, wc = wave & 1;
#pragma unroll
  for (int mi = 0; mi < 4; ++mi) {
    const int m0 = tm + wr * 64 + mi * 16 + quad * 4;
#pragma unroll
    for (int ni = 0; ni < 4; ++ni) {
      const int n = tn + wc * 64 + ni * 16 + l16;
#pragma unroll
      for (int r = 0; r < 4; ++r)
        out[(long)(m0 + r) * NP + n] = acc[mi][ni][r];
    }
  }
}

// ---------------------------------------------------------------------------
extern "C" void kernel_launch(void* const* d_in, const int* in_sizes, int n_in,
                              void* d_out, int out_size, void* d_ws, size_t ws_size,
                              hipStream_t stream) {
  const float* x    = (const float*)d_in[0];
  const int*   mask = (const int*)d_in[1];
  const float* Wq   = (const float*)d_in[2];
  const float* Wk   = (const float*)d_in[3];
  const float* Wv   = (const float*)d_in[4];
  const float* Wo   = (const float*)d_in[5];

  float* out  = (float*)d_out;                    // [B,S,P] fp32
  float* attn = out + (long)NM * NP;              // [B,H,S,S] fp32

  char* ws = (char*)d_ws;
  const size_t MB = 1024 * 1024;
  bf16_t* x_bf  = (bf16_t*)(ws);                  // 8 MB (aliased as o_ws later)
  bf16_t* wtq   = (bf16_t*)(ws + 8  * MB);        // 2 MB each
  bf16_t* wtk   = (bf16_t*)(ws + 10 * MB);
  bf16_t* wtv   = (bf16_t*)(ws + 12 * MB);
  bf16_t* wto   = (bf16_t*)(ws + 14 * MB);
  bf16_t* q_ws  = (bf16_t*)(ws + 16 * MB);        // 8 MB [b][h][s][dh], pre-scaled 1/8
  bf16_t* k_ws  = (bf16_t*)(ws + 24 * MB);        // 8 MB [b][h][s][dh]
  bf16_t* v_ws  = (bf16_t*)(ws + 32 * MB);        // 8 MB [b][h][dh][s]
  bf16_t* o_ws  = x_bf;  // safe: x_bf consumed by k_gemm_proj before k_attn_pv writes

  k_cast<<<1024, 256, 0, stream>>>(x, x_bf);
  k_wt<<<dim3(ND / 64, NP / 64, 4), 256, 0, stream>>>(
      Wq, Wk, Wv, Wo, wtq, wtk, wtv, wto);
  k_gemm_proj<<<dim3(NM / 128, NP / 128, 3), 256, 0, stream>>>(
      x_bf, wtq, wtk, wtv, q_ws, k_ws, v_ws);
  k_attn_pv<<<dim3(NS / 32, NH, NB), 256, 0, stream>>>(
      q_ws, k_ws, v_ws, mask, attn, o_ws);
  k_out<<<dim3(NM / 128, NP / 128), 256, 0, stream>>>(o_ws, wto, out);
}

// Round 5
// 890.694 us; speedup vs baseline: 1.3319x; 1.0494x over previous
//
#include <hip/hip_runtime.h>
#include <hip/hip_bf16.h>

typedef __bf16 bf16_t;
typedef __bf16 bf16x8 __attribute__((ext_vector_type(8)));
typedef float  f32x4  __attribute__((ext_vector_type(4)));
typedef unsigned int u32x4 __attribute__((ext_vector_type(4)));

#define NB 2
#define NS 2048
#define ND 1024
#define NH 16
#define NDH 64
#define NP 1024
#define NM (NB*NS)   // 4096 rows total

#define MFMA16 __builtin_amdgcn_mfma_f32_16x16x32_bf16

__device__ __forceinline__ bf16x8 load8(const bf16_t* p) {
  u32x4 u = *(const u32x4*)p;
  return __builtin_bit_cast(bf16x8, u);
}
__device__ __forceinline__ unsigned short bfb(float f) {
  return __builtin_bit_cast(unsigned short, (bf16_t)f);
}
// async global->LDS, 16B per lane; LDS dest must be wave-uniform base
__device__ __forceinline__ void gld16(const bf16_t* g, bf16_t* l) {
  __builtin_amdgcn_global_load_lds(
      (const __attribute__((address_space(1))) void*)g,
      (__attribute__((address_space(3))) void*)l, 16, 0, 0);
}

// ---------------------------------------------------------------------------
// Cast x -> bf16 (coalesced float4 -> ushort4)
// ---------------------------------------------------------------------------
__global__ __launch_bounds__(256) void k_cast(
    const float* __restrict__ x, bf16_t* __restrict__ x_bf)
{
  const long NX4 = (long)NM * ND / 4;   // 1M float4 items
  long i0 = (long)blockIdx.x * blockDim.x + threadIdx.x;
  long stride = (long)gridDim.x * blockDim.x;
  for (long i = i0; i < NX4; i += stride) {
    float4 v = ((const float4*)x)[i];
    ushort4 pk;
    pk.x = bfb(v.x); pk.y = bfb(v.y); pk.z = bfb(v.z); pk.w = bfb(v.w);
    ((ushort4*)x_bf)[i] = pk;
  }
}

// ---------------------------------------------------------------------------
// Weight transpose via LDS tile: fp32 [K][N] -> bf16 [N][K], coalesced both ways
// ---------------------------------------------------------------------------
__global__ __launch_bounds__(256) void k_wt(
    const float* __restrict__ Wq, const float* __restrict__ Wk,
    const float* __restrict__ Wv, const float* __restrict__ Wo,
    bf16_t* __restrict__ wtq, bf16_t* __restrict__ wtk,
    bf16_t* __restrict__ wtv, bf16_t* __restrict__ wto)
{
  __shared__ __align__(16) bf16_t tileT[64][72];  // [n][k], stride 144B
  const int w = blockIdx.z;
  const float* src = (w == 0) ? Wq : (w == 1) ? Wk : (w == 2) ? Wv : Wo;
  bf16_t*      dst = (w == 0) ? wtq : (w == 1) ? wtk : (w == 2) ? wtv : wto;
  const int k0 = blockIdx.x * 64, n0 = blockIdx.y * 64;
  const int tid = threadIdx.x;
  const int r = tid >> 4, c4 = (tid & 15) * 4;
#pragma unroll
  for (int rr = 0; rr < 4; ++rr) {
    const int row = rr * 16 + r;                  // k index within tile
    const float4 v = *(const float4*)&src[(long)(k0 + row) * NP + n0 + c4];
    tileT[c4 + 0][row] = (bf16_t)v.x;
    tileT[c4 + 1][row] = (bf16_t)v.y;
    tileT[c4 + 2][row] = (bf16_t)v.z;
    tileT[c4 + 3][row] = (bf16_t)v.w;
  }
  __syncthreads();
  const int nr = tid >> 2, kc = (tid & 3) * 16;
  const bf16x8 p0 = *(const bf16x8*)&tileT[nr][kc];
  const bf16x8 p1 = *(const bf16x8*)&tileT[nr][kc + 8];
  bf16_t* dp = dst + (long)(n0 + nr) * ND + k0 + kc;
  *(bf16x8*)dp = p0;
  *(bf16x8*)(dp + 8) = p1;
}

// ---------------------------------------------------------------------------
// m97-style 128x128 GEMM core: C = A[M x K] * Bt[N x K]^T, bf16 in, f32 acc.
// ---------------------------------------------------------------------------
template <int KDIM>
__device__ __forceinline__ void gemm_128x128(
    const bf16_t* __restrict__ A, const bf16_t* __restrict__ B,
    int tm, int tn, bf16_t (&As)[128][64], bf16_t (&Bs)[128][64],
    f32x4 (&acc)[4][4])
{
  const int wave = threadIdx.x >> 6, lane = threadIdx.x & 63;
  const int l16 = lane & 15, quad = lane >> 4;
  const int wr = wave >> 1, wc = wave & 1;
  const int srcrow = lane >> 3, srccol = (lane & 7) * 8;

  for (int ks = 0; ks < KDIM; ks += 64) {
#pragma unroll
    for (int i = 0; i < 4; ++i) {
      const int cc = i * 4 + wave;   // wave-uniform LDS dest
      gld16(A + (long)(tm + cc * 8 + srcrow) * KDIM + ks + srccol, &As[cc * 8][0]);
      gld16(B + (long)(tn + cc * 8 + srcrow) * KDIM + ks + srccol, &Bs[cc * 8][0]);
    }
    __syncthreads();   // drains vmcnt -> LDS tiles ready
#pragma unroll
    for (int s = 0; s < 2; ++s) {
      bf16x8 aF[4], bF[4];
#pragma unroll
      for (int t = 0; t < 4; ++t)
        aF[t] = load8(&As[wr * 64 + t * 16 + l16][s * 32 + quad * 8]);
#pragma unroll
      for (int t = 0; t < 4; ++t)
        bF[t] = load8(&Bs[wc * 64 + t * 16 + l16][s * 32 + quad * 8]);
#pragma unroll
      for (int mi = 0; mi < 4; ++mi)
#pragma unroll
        for (int ni = 0; ni < 4; ++ni)
          acc[mi][ni] = MFMA16(aF[mi], bF[ni], acc[mi][ni], 0, 0, 0);
    }
    __syncthreads();   // before next stage overwrites LDS
  }
}

// ---------------------------------------------------------------------------
// QKV projection: 128x128 LDS-staged GEMM. q pre-scaled 1/8 (exact pow2);
// q,k stored [b][h][s][dh]; v transposed [b][h][dh][s].
// ---------------------------------------------------------------------------
__global__ __launch_bounds__(256) void k_gemm_proj(
    const bf16_t* __restrict__ Abf,
    const bf16_t* __restrict__ wtq, const bf16_t* __restrict__ wtk,
    const bf16_t* __restrict__ wtv,
    bf16_t* __restrict__ q_ws, bf16_t* __restrict__ k_ws, bf16_t* __restrict__ v_ws)
{
  __shared__ __align__(16) bf16_t As[128][64];
  __shared__ __align__(16) bf16_t Bs[128][64];
  const int z = blockIdx.z;
  const bf16_t* Wt = (z == 0) ? wtq : (z == 1) ? wtk : wtv;
  const int tm = blockIdx.x * 128, tn = blockIdx.y * 128;

  f32x4 acc[4][4];
#pragma unroll
  for (int i = 0; i < 4; ++i)
#pragma unroll
    for (int j = 0; j < 4; ++j) acc[i][j] = (f32x4){0.f, 0.f, 0.f, 0.f};

  gemm_128x128<ND>(Abf, Wt, tm, tn, As, Bs, acc);

  const int wave = threadIdx.x >> 6, lane = threadIdx.x & 63;
  const int l16 = lane & 15, quad = lane >> 4;
  const int wr = wave >> 1, wc = wave & 1;
  const float qscale = (z == 0) ? 0.125f : 1.0f;
#pragma unroll
  for (int mi = 0; mi < 4; ++mi) {
    const int m0 = tm + wr * 64 + mi * 16 + quad * 4;
#pragma unroll
    for (int ni = 0; ni < 4; ++ni) {
      const int n = tn + wc * 64 + ni * 16 + l16;
      const int h = n >> 6, dh = n & 63;
      if (z == 2) {
        const int b = m0 >> 11, s0 = m0 & 2047;
        ushort4 pk;
        pk.x = bfb(acc[mi][ni][0]); pk.y = bfb(acc[mi][ni][1]);
        pk.z = bfb(acc[mi][ni][2]); pk.w = bfb(acc[mi][ni][3]);
        *(ushort4*)(v_ws + ((long)(b * NH + h) * NDH + dh) * NS + s0) = pk;
      } else {
        bf16_t* dst = (z == 0) ? q_ws : k_ws;
#pragma unroll
        for (int r = 0; r < 4; ++r) {
          const int m = m0 + r;
          const int b = m >> 11, s = m & 2047;
          dst[((long)(b * NH + h) * NS + s) * NDH + dh] = (bf16_t)(acc[mi][ni][r] * qscale);
        }
      }
    }
  }
}

// ---------------------------------------------------------------------------
// Fused attention, SINGLE QK sweep with full row-block e in fp32 LDS.
// Block = 16 q-rows x one head, 8 waves (512 thr), 1 block/CU (131 KB LDS).
//   phase 1: wave w computes QK+exp for k in [w*256, w*256+256), writes
//            unnormalized e to eT[16][2048] (fp32), accumulates rowsum parts.
//   barrier; rowsums combined -> inv per row.
//   phase 3 (issued first): stream NORMALIZED attn rows straight from LDS —
//            contiguous 8 KB per row, 1 KB per store instr (HBM-friendly).
//   phase 2: PV with UNNORMALIZED e (normalization commutes into O):
//            wave (kh,dt) accumulates k-half kh for dh-block dt; pairwise
//            cross-wave reduce; O *= inv at store.
// Removes: 2nd QK sweep (half the MFMA/exp/K-fetch) and in-loop LDS roundtrip.
// ---------------------------------------------------------------------------
__global__ __launch_bounds__(512) void k_attn_pv(
    const bf16_t* __restrict__ q_ws, const bf16_t* __restrict__ k_ws,
    const bf16_t* __restrict__ v_ws, const int* __restrict__ mask,
    float* __restrict__ attn, bf16_t* __restrict__ o_ws)
{
  constexpr int EP = 2052;                      // padded row stride (dwords), 16B-mult
  __shared__ __align__(16) float eT[16][EP];    // 131,328 B unnormalized exp
  __shared__ float sSum[8][16];                 // per-wave rowsum partials
  __shared__ __align__(16) float red[4][64][4]; // kh=1 PV partials (4 KB)
  const int qt = blockIdx.x, h = blockIdx.y, b = blockIdx.z;
  const int wave = threadIdx.x >> 6, lane = threadIdx.x & 63;
  const int l16 = lane & 15, quad = lane >> 4;
  const int qbase = qt * 16;
  const long headoff = (long)(b * NH + h) * NS;
  const bf16_t* qhead = q_ws + headoff * NDH;
  const bf16_t* khead = k_ws + headoff * NDH;
  const bf16_t* vhead = v_ws + (long)(b * NH + h) * NDH * NS;
  const bf16x8 aq0 = load8(qhead + (long)(qbase + l16) * NDH + quad * 8);
  const bf16x8 aq1 = load8(qhead + (long)(qbase + l16) * NDH + 32 + quad * 8);
  const int* mrow = mask + b * NS;

  // ---- phase 1: one QK+exp pass over this wave's k-range ----
  float s0 = 0.f, s1 = 0.f, s2 = 0.f, s3 = 0.f;
  const int kb1 = wave * 256;
#pragma unroll 2
  for (int k0 = kb1; k0 < kb1 + 256; k0 += 64) {
#pragma unroll
    for (int nt = 0; nt < 4; ++nt) {
      const bf16_t* kr = khead + (long)(k0 + nt * 16 + l16) * NDH;
      f32x4 acc = {0.f, 0.f, 0.f, 0.f};
      acc = MFMA16(aq0, load8(kr + quad * 8), acc, 0, 0, 0);
      acc = MFMA16(aq1, load8(kr + 32 + quad * 8), acc, 0, 0, 0);
      const int col = k0 + nt * 16 + l16;
      const int mv = mrow[col];
      float e0 = mv ? __expf(acc[0]) : 0.f;
      float e1 = mv ? __expf(acc[1]) : 0.f;
      float e2 = mv ? __expf(acc[2]) : 0.f;
      float e3 = mv ? __expf(acc[3]) : 0.f;
      eT[quad * 4 + 0][col] = e0;
      eT[quad * 4 + 1][col] = e1;
      eT[quad * 4 + 2][col] = e2;
      eT[quad * 4 + 3][col] = e3;
      s0 += e0; s1 += e1; s2 += e2; s3 += e3;
    }
  }
  s0 += __shfl_xor(s0, 1); s0 += __shfl_xor(s0, 2); s0 += __shfl_xor(s0, 4); s0 += __shfl_xor(s0, 8);
  s1 += __shfl_xor(s1, 1); s1 += __shfl_xor(s1, 2); s1 += __shfl_xor(s1, 4); s1 += __shfl_xor(s1, 8);
  s2 += __shfl_xor(s2, 1); s2 += __shfl_xor(s2, 2); s2 += __shfl_xor(s2, 4); s2 += __shfl_xor(s2, 8);
  s3 += __shfl_xor(s3, 1); s3 += __shfl_xor(s3, 2); s3 += __shfl_xor(s3, 4); s3 += __shfl_xor(s3, 8);
  if (l16 == 0) {
    sSum[wave][quad * 4 + 0] = s0;
    sSum[wave][quad * 4 + 1] = s1;
    sSum[wave][quad * 4 + 2] = s2;
    sSum[wave][quad * 4 + 3] = s3;
  }
  __syncthreads();

  float inv[4];
#pragma unroll
  for (int r = 0; r < 4; ++r) {
    const int row = quad * 4 + r;
    inv[r] = 1.0f / (((sSum[0][row] + sSum[1][row]) + (sSum[2][row] + sSum[3][row])) +
                     ((sSum[4][row] + sSum[5][row]) + (sSum[6][row] + sSum[7][row])));
  }

  // ---- phase 3 (issued first): stream normalized attn rows from LDS ----
#pragma unroll
  for (int rr = 0; rr < 2; ++rr) {
    const int row = wave * 2 + rr;
    const float ir = 1.0f / (((sSum[0][row] + sSum[1][row]) + (sSum[2][row] + sSum[3][row])) +
                             ((sSum[4][row] + sSum[5][row]) + (sSum[6][row] + sSum[7][row])));
    float* dst = attn + (headoff + qbase + row) * NS;
    const float* src = &eT[row][0];
#pragma unroll
    for (int c = 0; c < NS; c += 256) {
      f32x4 v4 = *(const f32x4*)(src + c + lane * 4);
      v4 *= ir;
      *(f32x4*)(dst + c + lane * 4) = v4;
    }
  }

  // ---- phase 2: PV with unnormalized e; wave = (kh, dt) ----
  const int dt = wave & 3, kh = wave >> 2;
  f32x4 acco = {0.f, 0.f, 0.f, 0.f};
  const bf16_t* vrow = vhead + (long)(dt * 16 + l16) * NS;
  const int kb2 = kh * 1024;
#pragma unroll 2
  for (int k0 = kb2; k0 < kb2 + 1024; k0 += 64) {
    const float* ep = &eT[l16][k0 + quad * 8];
    f32x4 ea = *(const f32x4*)ep;
    f32x4 eb = *(const f32x4*)(ep + 4);
    f32x4 ec = *(const f32x4*)(ep + 32);
    f32x4 ed = *(const f32x4*)(ep + 36);
    bf16x8 af0, af1;
#pragma unroll
    for (int i = 0; i < 4; ++i) {
      af0[i] = (bf16_t)ea[i]; af0[i + 4] = (bf16_t)eb[i];
      af1[i] = (bf16_t)ec[i]; af1[i + 4] = (bf16_t)ed[i];
    }
    acco = MFMA16(af0, load8(vrow + k0 + quad * 8), acco, 0, 0, 0);
    acco = MFMA16(af1, load8(vrow + k0 + 32 + quad * 8), acco, 0, 0, 0);
  }
  if (kh == 1) *(f32x4*)&red[dt][lane][0] = acco;
  __syncthreads();
  if (kh == 0) {
    f32x4 o = acco + *(const f32x4*)&red[dt][lane][0];
#pragma unroll
    for (int r = 0; r < 4; ++r)
      o_ws[(long)(b * NS + qbase + quad * 4 + r) * NP + h * NDH + dt * 16 + l16] =
          (bf16_t)(o[r] * inv[r]);
  }
}

// ---------------------------------------------------------------------------
// out = O @ Wo  (128x128 LDS-staged GEMM, fp32 store to d_out)
// ---------------------------------------------------------------------------
__global__ __launch_bounds__(256) void k_out(
    const bf16_t* __restrict__ o_ws, const bf16_t* __restrict__ wto,
    float* __restrict__ out)
{
  __shared__ __align__(16) bf16_t As[128][64];
  __shared__ __align__(16) bf16_t Bs[128][64];
  const int tm = blockIdx.x * 128, tn = blockIdx.y * 128;

  f32x4 acc[4][4];
#pragma unroll
  for (int i = 0; i < 4; ++i)
#pragma unroll
    for (int j = 0; j < 4; ++j) acc[i][j] = (f32x4){0.f, 0.f, 0.f, 0.f};

  gemm_128x128<NP>(o_ws, wto, tm, tn, As, Bs, acc);

  const int wave = threadIdx.x >> 6, lane = threadIdx.x & 63;
  const int l16 = lane & 15, quad = lane >> 4;
  const int wr = wave >> 1, wc = wave & 1;
#pragma unroll
  for (int mi = 0; mi < 4; ++mi) {
    const int m0 = tm + wr * 64 + mi * 16 + quad * 4;
#pragma unroll
    for (int ni = 0; ni < 4; ++ni) {
      const int n = tn + wc * 64 + ni * 16 + l16;
#pragma unroll
      for (int r = 0; r < 4; ++r)
        out[(long)(m0 + r) * NP + n] = acc[mi][ni][r];
    }
  }
}

// ---------------------------------------------------------------------------
extern "C" void kernel_launch(void* const* d_in, const int* in_sizes, int n_in,
                              void* d_out, int out_size, void* d_ws, size_t ws_size,
                              hipStream_t stream) {
  const float* x    = (const float*)d_in[0];
  const int*   mask = (const int*)d_in[1];
  const float* Wq   = (const float*)d_in[2];
  const float* Wk   = (const float*)d_in[3];
  const float* Wv   = (const float*)d_in[4];
  const float* Wo   = (const float*)d_in[5];

  float* out  = (float*)d_out;                    // [B,S,P] fp32
  float* attn = out + (long)NM * NP;              // [B,H,S,S] fp32

  char* ws = (char*)d_ws;
  const size_t MB = 1024 * 1024;
  bf16_t* x_bf  = (bf16_t*)(ws);                  // 8 MB (aliased as o_ws later)
  bf16_t* wtq   = (bf16_t*)(ws + 8  * MB);        // 2 MB each
  bf16_t* wtk   = (bf16_t*)(ws + 10 * MB);
  bf16_t* wtv   = (bf16_t*)(ws + 12 * MB);
  bf16_t* wto   = (bf16_t*)(ws + 14 * MB);
  bf16_t* q_ws  = (bf16_t*)(ws + 16 * MB);        // 8 MB [b][h][s][dh], pre-scaled 1/8
  bf16_t* k_ws  = (bf16_t*)(ws + 24 * MB);        // 8 MB [b][h][s][dh]
  bf16_t* v_ws  = (bf16_t*)(ws + 32 * MB);        // 8 MB [b][h][dh][s]
  bf16_t* o_ws  = x_bf;  // safe: x_bf consumed by k_gemm_proj before k_attn_pv writes

  k_cast<<<1024, 256, 0, stream>>>(x, x_bf);
  k_wt<<<dim3(ND / 64, NP / 64, 4), 256, 0, stream>>>(
      Wq, Wk, Wv, Wo, wtq, wtk, wtv, wto);
  k_gemm_proj<<<dim3(NM / 128, NP / 128, 3), 256, 0, stream>>>(
      x_bf, wtq, wtk, wtv, q_ws, k_ws, v_ws);
  k_attn_pv<<<dim3(NS / 16, NH, NB), 512, 0, stream>>>(
      q_ws, k_ws, v_ws, mask, attn, o_ws);
  k_out<<<dim3(NM / 128, NP / 128), 256, 0, stream>>>(o_ws, wto, out);
}